// Round 19
// baseline (526.561 us; speedup 1.0000x reference)
//
#include <hip/hip_runtime.h>
#include <math.h>

#define BATCH 4
#define NSEQ 8193
#define CDIM 768
#define TOPK 12
#define NCHUNK 32      // 32 chunks x 256 tokens (2 subs of 128)
#define NSUB 64        // 64 subchunks x 128 tokens (V candidate granularity)
#define PCV 12         // per-subchunk V candidates (packed u32)
#define NCAND 16       // global V candidates, fp64-rescored (R4/R17 precedent)
#define NDBLK 12       // 768 / 64
#define KSTEP 32
#define NT 24          // 768/32
#define ROWSTRIDE 40   // bf16 elems per LDS row (32 data + 8 pad = 80B)
#define STGE 12800     // bf16 elems per staging buffer: 320 rows * 40
#define STGB 25600     // bytes per staging buffer
#define WOFF 10240     // byte offset of W region within a staging buffer
#define NCLSB 2304     // cls blocks: 9216 outputs / 4 waves per block

typedef __attribute__((ext_vector_type(8))) __bf16 bf16x8;
typedef __attribute__((ext_vector_type(4))) __bf16 bf16x4;
typedef __attribute__((ext_vector_type(4))) float f32x4;

// ---------- top-k insertion helpers ----------
__device__ __forceinline__ void ins_f(float v, float (&lst)[TOPK]) {
  if (v > lst[TOPK - 1]) {
#pragma unroll
    for (int r = 0; r < TOPK; ++r) {
      bool g = v > lst[r];
      float disp = g ? lst[r] : v;
      lst[r] = g ? v : lst[r];
      v = disp;
    }
  }
}

template <int DP>
__device__ __forceinline__ void ins_u(unsigned v, unsigned (&lst)[DP]) {
  if (v > lst[DP - 1]) {
#pragma unroll
    for (int r = 0; r < DP; ++r) {
      bool g = v > lst[r];
      unsigned dv = g ? lst[r] : v;
      lst[r] = g ? v : lst[r];
      v = dv;
    }
  }
}

__device__ __forceinline__ void ins_di(double v, int i, double (&lv)[TOPK], int (&li)[TOPK]) {
#pragma unroll
  for (int r = 0; r < TOPK; ++r) {
    bool g = (v > lv[r]) || (v == lv[r] && i < li[r]);
    double dv = g ? lv[r] : v;
    int di = g ? li[r] : i;
    lv[r] = g ? v : lv[r];
    li[r] = g ? i : li[r];
    v = dv;
    i = di;
  }
}

// value-ordered sortable key with embedded token index (13 bits)
__device__ __forceinline__ unsigned sortkey(float f, int idx) {
  unsigned u = __float_as_uint(f);
  u = (u & 0x80000000u) ? ~u : (u | 0x80000000u);
  return (u & 0xFFFFE000u) | (unsigned)idx;
}

// ---------- kernel A+W fused: cls QKV rows wave-parallel (blocks 0..2303) | W cvt (rest) ----------
__global__ void cls_wconv_kernel(const float* __restrict__ x, const float* __restrict__ W,
                                 const float* __restrict__ bias, float* __restrict__ cls,
                                 __bf16* __restrict__ wh) {
  const int blk = blockIdx.x, tid = threadIdx.x;
  if (blk < NCLSB) {
    const int idx = blk * 4 + (tid >> 6);  // output index [0, 9216)
    const int l = tid & 63;
    const int qty = idx / (BATCH * CDIM);
    const int rem = idx % (BATCH * CDIM);
    const int b = rem / CDIM;
    const int d = rem % CDIM;
    const int o = qty * CDIM + d;
    const float* xr = x + (size_t)b * NSEQ * CDIM + l * 12;  // token-0 row slice
    const float* wr = W + (size_t)o * CDIM + l * 12;
    float4 a0 = *(const float4*)(xr + 0);
    float4 a1 = *(const float4*)(xr + 4);
    float4 a2 = *(const float4*)(xr + 8);
    float4 w0 = *(const float4*)(wr + 0);
    float4 w1 = *(const float4*)(wr + 4);
    float4 w2 = *(const float4*)(wr + 8);
    float s = 0.f;
    s = fmaf(a0.x, w0.x, s); s = fmaf(a0.y, w0.y, s);
    s = fmaf(a0.z, w0.z, s); s = fmaf(a0.w, w0.w, s);
    s = fmaf(a1.x, w1.x, s); s = fmaf(a1.y, w1.y, s);
    s = fmaf(a1.z, w1.z, s); s = fmaf(a1.w, w1.w, s);
    s = fmaf(a2.x, w2.x, s); s = fmaf(a2.y, w2.y, s);
    s = fmaf(a2.z, w2.z, s); s = fmaf(a2.w, w2.w, s);
#pragma unroll
    for (int off = 32; off > 0; off >>= 1) s += __shfl_xor(s, off, 64);  // deterministic tree
    if (l == 0) cls[qty * (BATCH * CDIM) + b * CDIM + d] = s + bias[o];
  } else {
    int i = ((blk - NCLSB) * 256 + tid) * 4;  // 1728 blocks cover 2304*768 exactly
    float4 v = *(const float4*)(W + i);
    bf16x4 o = {(__bf16)v.x, (__bf16)v.y, (__bf16)v.z, (__bf16)v.w};
    *(bf16x4*)(wh + i) = o;
  }
}

// ---------- kernel B: R10-proven fused MFMA GEMM; m-write non-temporal (ext-vector type) ----------
// FETCH analysis (R17: 175MB = x 100 + W ~16x re-fetch): the 100MB write-once m-map
// streams through each XCD's 4MB L2 and evicts W between k-tiles. nt stores fix that.
__launch_bounds__(256, 2)
__global__ void fused_kernel(const float* __restrict__ x, const __bf16* __restrict__ wh,
                             const float* __restrict__ bias, const float* __restrict__ cls,
                             float* __restrict__ out,
                             float* __restrict__ candQ, float* __restrict__ candK,
                             unsigned* __restrict__ candV) {
  __shared__ __align__(16) union SM {
    __bf16 stg[2][STGE];          // 2 x 25600B; x rows 0..127 @ r*80B, W rows @ 10240 + r*80B
    float bufq[128][68];          // 34816B epilogue redistribution
    float part[4][64][13];
    unsigned partu[4][64][13];
  } sm;

  const int tid = threadIdx.x;
  // XCD-aware swizzle (proven R8/R10)
  const int g = blockIdx.x;            // 0..1535
  const int xcd = g & 7;
  const int r_ = g >> 3;               // 0..191
  const int dblk = r_ % 12;
  const int cg = (r_ / 12) * 8 + xcd;  // chunk-group 0..127
  const int chunk = cg & 31;
  const int b = cg >> 5;

  const int d0 = dblk * 64;
  const int w = tid >> 6, l = tid & 63;
  const int wr = w >> 1, wc = w & 1;   // wave 2x2 over (row-tiles, col-halves)
  const int lg = l >> 4, lc = l & 15;
  const int sq = tid >> 6, sd = tid & 63;

  // x staging roles (k0-independent)
  const int xrow = tid >> 1, xh_ = tid & 1;  // x: row 0..127, 16-float half

  // W staging: 960 slots of 16B (192 rows x 5 slots; slot 4 duplicates slot 3 into pad)
  const char* whc = (const char*)wh;
  unsigned wsoff[4];
#pragma unroll
  for (int i = 0; i < 4; ++i) {
    int sl = tid + (i << 8);
    unsigned off = 0;
    if (sl < 960) {
      int row = sl / 5, o = sl % 5;
      int oc = (o > 3) ? 3 : o;
      off = (unsigned)((((row >> 6) * CDIM + d0 + (row & 63)) * (CDIM * 2)) + oc * 16);
    }
    wsoff[i] = off;
  }

  // per-lane cls/bias constants for its 2 column groups
  float qc2[2], kc2[2], iv2[2], bq2[2], bk2[2], bv2[2];
#pragma unroll
  for (int tc = 0; tc < 2; ++tc) {
    int d = d0 + wc * 32 + tc * 16 + lc;
    float q_ = cls[0 * (BATCH * CDIM) + b * CDIM + d];
    float k_ = cls[1 * (BATCH * CDIM) + b * CDIM + d];
    float v_ = cls[2 * (BATCH * CDIM) + b * CDIM + d];
    qc2[tc] = q_; kc2[tc] = k_;
    iv2[tc] = (q_ * k_) * (1.0f + fabsf(v_));
    bq2[tc] = bias[d]; bk2[tc] = bias[CDIM + d]; bv2[tc] = bias[2 * CDIM + d];
  }

  // persistent Q/K per-thread quarter lists (across subs)
  float tqp[TOPK], tkp[TOPK];
#pragma unroll
  for (int r = 0; r < TOPK; ++r) { tqp[r] = -INFINITY; tkp[r] = -INFINITY; }

  for (int sub = 0; sub < 2; ++sub) {
    const int n0 = 1 + chunk * 256 + sub * 128;
    const float* xrp = x + (size_t)(b * NSEQ + n0 + xrow) * CDIM;  // this thread's x row

    f32x4 acc[4][2][3];
    const f32x4 zz = {0.f, 0.f, 0.f, 0.f};
#pragma unroll
    for (int rt = 0; rt < 4; ++rt)
#pragma unroll
      for (int tc = 0; tc < 2; ++tc)
#pragma unroll
        for (int q = 0; q < 3; ++q) acc[rt][tc][q] = zz;

    // x staging registers
    float4 xa0, xa1, xa2, xa3;

#define LOADT(T)                                                                      \
    {                                                                                 \
      const float* xp = xrp + (T) * KSTEP + xh_ * 16;                                 \
      xa0 = *(const float4*)(xp + 0);                                                 \
      xa1 = *(const float4*)(xp + 4);                                                 \
      xa2 = *(const float4*)(xp + 8);                                                 \
      xa3 = *(const float4*)(xp + 12);                                                \
    }

#define CVTWR(NB)                                                                     \
    {                                                                                 \
      __bf16* base_ = &sm.stg[NB][0];                                                 \
      bf16x8 lo, hi;                                                                  \
      lo[0] = (__bf16)xa0.x; lo[1] = (__bf16)xa0.y; lo[2] = (__bf16)xa0.z; lo[3] = (__bf16)xa0.w; \
      lo[4] = (__bf16)xa1.x; lo[5] = (__bf16)xa1.y; lo[6] = (__bf16)xa1.z; lo[7] = (__bf16)xa1.w; \
      hi[0] = (__bf16)xa2.x; hi[1] = (__bf16)xa2.y; hi[2] = (__bf16)xa2.z; hi[3] = (__bf16)xa2.w; \
      hi[4] = (__bf16)xa3.x; hi[5] = (__bf16)xa3.y; hi[6] = (__bf16)xa3.z; hi[7] = (__bf16)xa3.w; \
      *(bf16x8*)(base_ + xrow * ROWSTRIDE + xh_ * 16) = lo;                           \
      *(bf16x8*)(base_ + xrow * ROWSTRIDE + xh_ * 16 + 8) = hi;                       \
    }

#define WSTAGE(NB, T)                                                                 \
    {                                                                                 \
      __attribute__((address_space(3))) char* db =                                    \
          (__attribute__((address_space(3))) char*)&sm + (NB) * STGB + WOFF;          \
      _Pragma("unroll")                                                               \
      for (int i = 0; i < 4; ++i) {                                                   \
        int sl = tid + (i << 8);                                                      \
        if (sl < 960)                                                                 \
          __builtin_amdgcn_global_load_lds(                                           \
              (const __attribute__((address_space(1))) unsigned*)(const void*)(whc + wsoff[i] + (T) * 64), \
              (__attribute__((address_space(3))) unsigned*)(db + sl * 16), 16, 0, 0); \
      }                                                                               \
    }

    __syncthreads();  // stg region free of prior-phase (bufq) use
    WSTAGE(0, 0);
    LOADT(0);
    CVTWR(0);         // data-dep waits on its own x loads only
    for (int t = 0; t < NT; ++t) {
      __syncthreads();  // buf[t&1] x-writes + W DMA drained
      if (t + 1 < NT) {
        WSTAGE((t + 1) & 1, t + 1);  // async DMA into other buffer
        LOADT(t + 1);                // issue next x loads early
      }
      {
        const __bf16* smc = &sm.stg[t & 1][0];
        bf16x8 bfr[2][3];
#pragma unroll
        for (int tc = 0; tc < 2; ++tc)
#pragma unroll
          for (int q = 0; q < 3; ++q)
            bfr[tc][q] = *(const bf16x8*)(smc + (128 + q * 64 + wc * 32 + tc * 16 + lc) * ROWSTRIDE + lg * 8);
#pragma unroll
        for (int rt = 0; rt < 4; ++rt) {
          bf16x8 af = *(const bf16x8*)(smc + (wr * 64 + rt * 16 + lc) * ROWSTRIDE + lg * 8);
#pragma unroll
          for (int tc = 0; tc < 2; ++tc)
#pragma unroll
            for (int q = 0; q < 3; ++q)
              acc[rt][tc][q] = __builtin_amdgcn_mfma_f32_16x16x32_bf16(af, bfr[tc][q], acc[rt][tc][q], 0, 0, 0);
        }
      }
      if (t + 1 < NT) CVTWR((t + 1) & 1);  // write other buffer (disjoint from reads)
    }
#undef LOADT
#undef CVTWR
#undef WSTAGE
    __syncthreads();  // last tile's ds_reads done before bufq overwrite

    // bias
#pragma unroll
    for (int rt = 0; rt < 4; ++rt)
#pragma unroll
      for (int tc = 0; tc < 2; ++tc)
#pragma unroll
        for (int r = 0; r < 4; ++r) {
          acc[rt][tc][0][r] += bq2[tc];
          acc[rt][tc][1][r] += bk2[tc];
          acc[rt][tc][2][r] += bv2[tc];
        }

    // ======== pass V: m = v^2+2v+iv
#pragma unroll
    for (int rt = 0; rt < 4; ++rt)
#pragma unroll
      for (int tc = 0; tc < 2; ++tc)
#pragma unroll
        for (int r = 0; r < 4; ++r) {
          float v = acc[rt][tc][2][r];
          sm.bufq[wr * 64 + rt * 16 + lg * 4 + r][wc * 32 + tc * 16 + lc] = fmaf(v, v + 2.0f, iv2[tc]);
        }
    __syncthreads();
    unsigned tv[PCV];
#pragma unroll
    for (int r = 0; r < PCV; ++r) tv[r] = 0u;
    {
      const int gb = chunk * 256 + sub * 128;
      for (int t = sq * 32; t < sq * 32 + 32; ++t)
        ins_u<PCV>(sortkey(sm.bufq[t][sd], gb + t), tv);
    }
    {  // m-map -> out rows: NON-TEMPORAL (write-once, never re-read; keep W in L2)
      int row = tid >> 1, h = tid & 1;
      float* orow = out + ((size_t)(b * NSEQ + n0 + row)) * CDIM + d0 + h * 32;
#pragma unroll
      for (int i = 0; i < 8; ++i)
        __builtin_nontemporal_store(*(const f32x4*)&sm.bufq[row][h * 32 + i * 4],
                                    (f32x4*)(orow + i * 4));
    }
    __syncthreads();
#pragma unroll
    for (int r = 0; r < PCV; ++r) sm.partu[sq][sd][r] = tv[r];
    __syncthreads();
    if (tid < 64) {
      for (int qq = 1; qq < 4; ++qq)
#pragma unroll
        for (int r = 0; r < PCV; ++r) ins_u<PCV>(sm.partu[qq][tid][r], tv);
      size_t base = ((size_t)(b * CDIM + d0 + tid) * NSUB + (chunk * 2 + sub)) * PCV;
#pragma unroll
      for (int r = 0; r < PCV; ++r) candV[base + r] = tv[r];
    }

    // ======== pass Q: a_q = q_cls*k + q
    __syncthreads();
#pragma unroll
    for (int rt = 0; rt < 4; ++rt)
#pragma unroll
      for (int tc = 0; tc < 2; ++tc)
#pragma unroll
        for (int r = 0; r < 4; ++r)
          sm.bufq[wr * 64 + rt * 16 + lg * 4 + r][wc * 32 + tc * 16 + lc] =
              fmaf(qc2[tc], acc[rt][tc][1][r], acc[rt][tc][0][r]);
    __syncthreads();
    for (int t = sq * 32; t < sq * 32 + 32; ++t) ins_f(sm.bufq[t][sd], tqp);

    // ======== pass K: a_k = k_cls*q + k
    __syncthreads();
#pragma unroll
    for (int rt = 0; rt < 4; ++rt)
#pragma unroll
      for (int tc = 0; tc < 2; ++tc)
#pragma unroll
        for (int r = 0; r < 4; ++r)
          sm.bufq[wr * 64 + rt * 16 + lg * 4 + r][wc * 32 + tc * 16 + lc] =
              fmaf(kc2[tc], acc[rt][tc][0][r], acc[rt][tc][1][r]);
    __syncthreads();
    for (int t = sq * 32; t < sq * 32 + 32; ++t) ins_f(sm.bufq[t][sd], tkp);
    // next sub's top barrier protects stg overwrite of bufq
  }  // sub

  // ---- merge Q partials, write candQ
  __syncthreads();
#pragma unroll
  for (int r = 0; r < TOPK; ++r) sm.part[sq][sd][r] = tqp[r];
  __syncthreads();
  if (tid < 64) {
    for (int qq = 1; qq < 4; ++qq)
#pragma unroll
      for (int r = 0; r < TOPK; ++r) ins_f(sm.part[qq][tid][r], tqp);
    size_t base = ((size_t)(b * CDIM + d0 + tid) * NCHUNK + chunk) * TOPK;
#pragma unroll
    for (int r = 0; r < TOPK; ++r) candQ[base + r] = tqp[r];
  }
  // ---- merge K partials, write candK
  __syncthreads();
#pragma unroll
  for (int r = 0; r < TOPK; ++r) sm.part[sq][sd][r] = tkp[r];
  __syncthreads();
  if (tid < 64) {
    for (int qq = 1; qq < 4; ++qq)
#pragma unroll
      for (int r = 0; r < TOPK; ++r) ins_f(sm.part[qq][tid][r], tkp);
    size_t base = ((size_t)(b * CDIM + d0 + tid) * NCHUNK + chunk) * TOPK;
#pragma unroll
    for (int r = 0; r < TOPK; ++r) candK[base + r] = tkp[r];
  }
}

// ---------- kernel C+E fused: merges, rebalanced 32 pairs x 8 groups (grid 96) ----------
__global__ void merge2_kernel(const float* __restrict__ cls,
                              const float* __restrict__ candQ, const float* __restrict__ candK,
                              const unsigned* __restrict__ candV,
                              float* __restrict__ qm, float* __restrict__ km,
                              float* __restrict__ vm, int* __restrict__ cVi) {
  __shared__ union {
    struct { float pq[8][32][13]; float pk[8][32][13]; } qk;
    unsigned pu[8][32][NCAND];
  } s;
  const int tid = threadIdx.x;
  const int c = tid & 31;
  const int q = tid >> 5;              // group 0..7
  const int pr = blockIdx.x * 32 + c;  // (b,d) pair index

  // ---- phase A: Q/K merge (group scans NCHUNK/8 = 4 chunks)
  float tq[TOPK], tk[TOPK];
#pragma unroll
  for (int r = 0; r < TOPK; ++r) { tq[r] = -INFINITY; tk[r] = -INFINITY; }
  {
    size_t base = ((size_t)pr * NCHUNK + q * 4) * TOPK;
    for (int cc = 0; cc < 4 * TOPK; ++cc) {
      ins_f(candQ[base + cc], tq);
      ins_f(candK[base + cc], tk);
    }
  }
#pragma unroll
  for (int r = 0; r < TOPK; ++r) { s.qk.pq[q][c][r] = tq[r]; s.qk.pk[q][c][r] = tk[r]; }
  __syncthreads();
  if (tid < 32) {
    for (int qq = 1; qq < 8; ++qq)
#pragma unroll
      for (int r = 0; r < TOPK; ++r) { ins_f(s.qk.pq[qq][tid][r], tq); ins_f(s.qk.pk[qq][tid][r], tk); }
    int pr2 = blockIdx.x * 32 + tid;
    int b = pr2 / CDIM, d = pr2 % CDIM;
    qm[(size_t)(b * 13 + 0) * CDIM + d] = cls[0 * (BATCH * CDIM) + b * CDIM + d];
    km[(size_t)(b * 13 + 0) * CDIM + d] = cls[1 * (BATCH * CDIM) + b * CDIM + d];
    vm[(size_t)(b * 13 + 0) * CDIM + d] = cls[2 * (BATCH * CDIM) + b * CDIM + d];
#pragma unroll
    for (int r = 0; r < TOPK; ++r) {
      qm[(size_t)(b * 13 + 1 + r) * CDIM + d] = tq[r];
      km[(size_t)(b * 13 + 1 + r) * CDIM + d] = tk[r];
    }
  }
  __syncthreads();  // phase A LDS reads done before phase B overwrites (union)

  // ---- phase B: V merge -> global top-16 indices (group scans NSUB/8 = 8 subchunks)
  unsigned lv[NCAND];
#pragma unroll
  for (int r = 0; r < NCAND; ++r) lv[r] = 0u;
  {
    size_t base = ((size_t)pr * NSUB + q * 8) * PCV;
    for (int i = 0; i < 8 * PCV; ++i) ins_u<NCAND>(candV[base + i], lv);
  }
#pragma unroll
  for (int r = 0; r < NCAND; ++r) s.pu[q][c][r] = lv[r];
  __syncthreads();
  if (tid < 32) {
    for (int qq = 1; qq < 8; ++qq)
#pragma unroll
      for (int r = 0; r < NCAND; ++r) ins_u<NCAND>(s.pu[qq][tid][r], lv);
    size_t ob = (size_t)(blockIdx.x * 32 + tid) * NCAND;
#pragma unroll
    for (int r = 0; r < NCAND; ++r) cVi[ob + r] = (int)(lv[r] & 0x1FFFu);
  }
}

// ---------- kernel F+D1 fused: fp64 rescore (blocks x<768) | 13x13 QK^T+softmax (x==768) ----------
__global__ void rescore_attn1_kernel(const float* __restrict__ x, const float* __restrict__ W,
                                     const float* __restrict__ bias, const float* __restrict__ cls,
                                     const int* __restrict__ cVi,
                                     const float* __restrict__ qm, const float* __restrict__ km,
                                     float* __restrict__ vm, int* __restrict__ vidx,
                                     float* __restrict__ attw) {
  const int tid = threadIdx.x;
  const int b = blockIdx.y;
  __shared__ union {
    struct { float wrow[CDIM]; int sidx[NCAND]; double sval[NCAND]; } rs;
    float att[13][16];
  } s;

  if (blockIdx.x == CDIM) {
    // ---- attn1: qm/km complete (merge2 launched earlier on stream)
    if (tid < 169) {
      int i = tid / 13, j = tid % 13;
      const float* qr = qm + (size_t)(b * 13 + i) * CDIM;
      const float* kr = km + (size_t)(b * 13 + j) * CDIM;
      float s0 = 0.f, s1 = 0.f, s2 = 0.f, s3 = 0.f;
      for (int c = 0; c < CDIM; c += 4) {
        s0 = fmaf(qr[c + 0], kr[c + 0], s0);
        s1 = fmaf(qr[c + 1], kr[c + 1], s1);
        s2 = fmaf(qr[c + 2], kr[c + 2], s2);
        s3 = fmaf(qr[c + 3], kr[c + 3], s3);
      }
      s.att[i][j] = ((s0 + s1) + (s2 + s3)) * 0.03608439182435161f;  // 768^-0.5
    }
    __syncthreads();
    if (tid < 13) {
      float mx = -INFINITY;
      float e[13];
#pragma unroll
      for (int j = 0; j < 13; ++j) mx = fmaxf(mx, s.att[tid][j]);
      float sum = 0.f;
#pragma unroll
      for (int j = 0; j < 13; ++j) { e[j] = expf(s.att[tid][j] - mx); sum += e[j]; }
      float inv = 1.f / sum;
#pragma unroll
      for (int j = 0; j < 13; ++j) attw[(b * 13 + tid) * 16 + j] = e[j] * inv;
    }
    return;
  }

  // ---- rescore: d = blockIdx.x ; wave w covers candidates [w*4, w*4+4)
  const int d = blockIdx.x;
  const int w = tid >> 6, l = tid & 63;
  if (tid < 192) *(float4*)&s.rs.wrow[tid * 4] = *(const float4*)(W + (size_t)(2 * CDIM + d) * CDIM + tid * 4);
  if (tid >= 192 && tid < 192 + NCAND)
    s.rs.sidx[tid - 192] = cVi[((size_t)b * CDIM + d) * NCAND + (tid - 192)];
  __syncthreads();
#pragma unroll
  for (int c8 = 0; c8 < NCAND / 4; ++c8) {
    const int c = w * (NCAND / 4) + c8;
    const float* xr = x + ((size_t)b * NSEQ + 1 + s.rs.sidx[c]) * CDIM + l * 12;
    const float* wp = &s.rs.wrow[l * 12];
    float4 a0 = *(const float4*)xr;
    float4 a1 = *(const float4*)(xr + 4);
    float4 a2 = *(const float4*)(xr + 8);
    double sdot = 0.0;
    sdot = fma((double)a0.x, (double)wp[0], sdot);
    sdot = fma((double)a0.y, (double)wp[1], sdot);
    sdot = fma((double)a0.z, (double)wp[2], sdot);
    sdot = fma((double)a0.w, (double)wp[3], sdot);
    sdot = fma((double)a1.x, (double)wp[4], sdot);
    sdot = fma((double)a1.y, (double)wp[5], sdot);
    sdot = fma((double)a1.z, (double)wp[6], sdot);
    sdot = fma((double)a1.w, (double)wp[7], sdot);
    sdot = fma((double)a2.x, (double)wp[8], sdot);
    sdot = fma((double)a2.y, (double)wp[9], sdot);
    sdot = fma((double)a2.z, (double)wp[10], sdot);
    sdot = fma((double)a2.w, (double)wp[11], sdot);
#pragma unroll
    for (int off = 32; off > 0; off >>= 1) sdot += __shfl_xor(sdot, off, 64);  // deterministic tree
    if (l == 0) s.rs.sval[c] = sdot;
  }
  __syncthreads();
  if (tid < NCAND) {
    double v = s.rs.sval[tid] + (double)bias[2 * CDIM + d];
    double qc = (double)cls[0 * (BATCH * CDIM) + b * CDIM + d];
    double kc = (double)cls[1 * (BATCH * CDIM) + b * CDIM + d];
    double vc = (double)cls[2 * (BATCH * CDIM) + b * CDIM + d];
    double ivd = (qc * kc) * (1.0 + fabs(vc));
    s.rs.sval[tid] = fma(v, v + 2.0, ivd);
  }
  __syncthreads();
  if (tid == 0) {
    double lv[TOPK];
    int li[TOPK];
#pragma unroll
    for (int r = 0; r < TOPK; ++r) { lv[r] = -INFINITY; li[r] = 0x7fffffff; }
    for (int cc = 0; cc < NCAND; ++cc) ins_di(s.rs.sval[cc], s.rs.sidx[cc], lv, li);
#pragma unroll
    for (int r = 0; r < TOPK; ++r) {
      vm[(size_t)(b * 13 + 1 + r) * CDIM + d] = (float)lv[r];
      vidx[(size_t)(b * TOPK + r) * CDIM + d] = li[r];
    }
  }
}

// ---------- kernel D2: PV + scatter-add (one block per (b, out-row)) ----------
__global__ void attn2_kernel(const float* __restrict__ attw, const float* __restrict__ vm,
                             const int* __restrict__ vidx, float* __restrict__ out) {
  const int b = blockIdx.x, j = blockIdx.y, tid = threadIdx.x;
  __shared__ float arow[13];
  if (tid < 13) arow[tid] = attw[(b * 13 + j) * 16 + tid];
  __syncthreads();
  for (int d = tid; d < CDIM; d += 256) {
    float s = 0.f;
#pragma unroll
    for (int kk = 0; kk < 13; ++kk) s = fmaf(arow[kk], vm[(size_t)(b * 13 + kk) * CDIM + d], s);
    if (j == 0) {
      out[(size_t)b * NSEQ * CDIM + d] = s;
    } else {
      int t = vidx[(size_t)(b * TOPK + (j - 1)) * CDIM + d];
      out[((size_t)b * NSEQ + 1 + t) * CDIM + d] += s;
    }
  }
}

extern "C" void kernel_launch(void* const* d_in, const int* in_sizes, int n_in,
                              void* d_out, int out_size, void* d_ws, size_t ws_size,
                              hipStream_t stream) {
  const float* x = (const float*)d_in[0];
  const float* W = (const float*)d_in[1];
  const float* bias = (const float*)d_in[2];
  float* out = (float*)d_out;
  char* ws = (char*)d_ws;

  // R5-proven workspace layout: total 23,470,080 bytes
  float* cls = (float*)(ws + 0);               // 36864
  float* qm = (float*)(ws + 36864);            // 159744
  float* km = (float*)(ws + 196608);           // 159744
  float* vm = (float*)(ws + 356352);           // 159744
  int* vidx = (int*)(ws + 516096);             // 147456
  float* candQ = (float*)(ws + 663552);        // 4718592
  float* candK = (float*)(ws + 5382144);       // 4718592
  unsigned* candV = (unsigned*)(ws + 10100736);// 9437184
  int* cVi = (int*)(ws + 19537920);            // 393216 (16/pair used)
  __bf16* wh = (__bf16*)(ws + 19931136);       // 3538944 -> total 23470080
  float* attw = (float*)(ws + 663552);         // aliases candQ (dead after merge2)

  hipLaunchKernelGGL(cls_wconv_kernel, dim3(NCLSB + 1728), dim3(256), 0, stream, x, W, bias, cls, wh);
  hipLaunchKernelGGL(fused_kernel, dim3(NDBLK * NCHUNK * BATCH), dim3(256), 0, stream,
                     x, wh, bias, cls, out, candQ, candK, candV);
  hipLaunchKernelGGL(merge2_kernel, dim3(BATCH * CDIM / 32), dim3(256), 0, stream,
                     cls, candQ, candK, candV, qm, km, vm, cVi);
  hipLaunchKernelGGL(rescore_attn1_kernel, dim3(CDIM + 1, BATCH), dim3(256), 0, stream,
                     x, W, bias, cls, cVi, qm, km, vm, vidx, attw);
  hipLaunchKernelGGL(attn2_kernel, dim3(BATCH, 13), dim3(256), 0, stream, attw, vm, vidx, out);
}

// Round 20
// 483.617 us; speedup vs baseline: 1.0888x; 1.0888x over previous
//
#include <hip/hip_runtime.h>
#include <math.h>

#define BATCH 4
#define NSEQ 8193
#define CDIM 768
#define TOPK 12
#define NCHUNK 32      // 32 chunks x 256 tokens (2 subs of 128)
#define NSUB 64        // 64 subchunks x 128 tokens (V candidate granularity)
#define PCV 12         // per-subchunk V candidates (packed u32)
#define NCAND 16       // global V candidates, fp64-rescored (R4/R17 precedent)
#define NDBLK 12       // 768 / 64
#define KSTEP 32
#define NT 24          // 768/32
#define ROWSTRIDE 40   // bf16 elems per LDS row (32 data + 8 pad = 80B)
#define STGE 12800     // bf16 elems per staging buffer: 320 rows * 40
#define STGB 25600     // bytes per staging buffer
#define WOFF 10240     // byte offset of W region within a staging buffer
#define NCLSB 2304     // cls blocks: 9216 outputs / 4 waves per block

typedef __attribute__((ext_vector_type(8))) __bf16 bf16x8;
typedef __attribute__((ext_vector_type(4))) __bf16 bf16x4;
typedef __attribute__((ext_vector_type(4))) float f32x4;

// ---------- top-k insertion helpers ----------
__device__ __forceinline__ void ins_f(float v, float (&lst)[TOPK]) {
  if (v > lst[TOPK - 1]) {
#pragma unroll
    for (int r = 0; r < TOPK; ++r) {
      bool g = v > lst[r];
      float disp = g ? lst[r] : v;
      lst[r] = g ? v : lst[r];
      v = disp;
    }
  }
}

template <int DP>
__device__ __forceinline__ void ins_u(unsigned v, unsigned (&lst)[DP]) {
  if (v > lst[DP - 1]) {
#pragma unroll
    for (int r = 0; r < DP; ++r) {
      bool g = v > lst[r];
      unsigned dv = g ? lst[r] : v;
      lst[r] = g ? v : lst[r];
      v = dv;
    }
  }
}

__device__ __forceinline__ void ins_di(double v, int i, double (&lv)[TOPK], int (&li)[TOPK]) {
#pragma unroll
  for (int r = 0; r < TOPK; ++r) {
    bool g = (v > lv[r]) || (v == lv[r] && i < li[r]);
    double dv = g ? lv[r] : v;
    int di = g ? li[r] : i;
    lv[r] = g ? v : lv[r];
    li[r] = g ? i : li[r];
    v = dv;
    i = di;
  }
}

// value-ordered sortable key with embedded token index (13 bits)
__device__ __forceinline__ unsigned sortkey(float f, int idx) {
  unsigned u = __float_as_uint(f);
  u = (u & 0x80000000u) ? ~u : (u | 0x80000000u);
  return (u & 0xFFFFE000u) | (unsigned)idx;
}

// ---------- kernel A+W fused: cls QKV rows wave-parallel (blocks 0..2303) | W cvt (rest) ----------
__global__ void cls_wconv_kernel(const float* __restrict__ x, const float* __restrict__ W,
                                 const float* __restrict__ bias, float* __restrict__ cls,
                                 __bf16* __restrict__ wh) {
  const int blk = blockIdx.x, tid = threadIdx.x;
  if (blk < NCLSB) {
    const int idx = blk * 4 + (tid >> 6);  // output index [0, 9216)
    const int l = tid & 63;
    const int qty = idx / (BATCH * CDIM);
    const int rem = idx % (BATCH * CDIM);
    const int b = rem / CDIM;
    const int d = rem % CDIM;
    const int o = qty * CDIM + d;
    const float* xr = x + (size_t)b * NSEQ * CDIM + l * 12;  // token-0 row slice
    const float* wr = W + (size_t)o * CDIM + l * 12;
    float4 a0 = *(const float4*)(xr + 0);
    float4 a1 = *(const float4*)(xr + 4);
    float4 a2 = *(const float4*)(xr + 8);
    float4 w0 = *(const float4*)(wr + 0);
    float4 w1 = *(const float4*)(wr + 4);
    float4 w2 = *(const float4*)(wr + 8);
    float s = 0.f;
    s = fmaf(a0.x, w0.x, s); s = fmaf(a0.y, w0.y, s);
    s = fmaf(a0.z, w0.z, s); s = fmaf(a0.w, w0.w, s);
    s = fmaf(a1.x, w1.x, s); s = fmaf(a1.y, w1.y, s);
    s = fmaf(a1.z, w1.z, s); s = fmaf(a1.w, w1.w, s);
    s = fmaf(a2.x, w2.x, s); s = fmaf(a2.y, w2.y, s);
    s = fmaf(a2.z, w2.z, s); s = fmaf(a2.w, w2.w, s);
#pragma unroll
    for (int off = 32; off > 0; off >>= 1) s += __shfl_xor(s, off, 64);  // deterministic tree
    if (l == 0) cls[qty * (BATCH * CDIM) + b * CDIM + d] = s + bias[o];
  } else {
    int i = ((blk - NCLSB) * 256 + tid) * 4;  // 1728 blocks cover 2304*768 exactly
    float4 v = *(const float4*)(W + i);
    bf16x4 o = {(__bf16)v.x, (__bf16)v.y, (__bf16)v.z, (__bf16)v.w};
    *(bf16x4*)(wh + i) = o;
  }
}

// ---------- kernel B: R10/R17-proven fused MFMA GEMM (447us, session optimum) ----------
// 256 thr, reg-staged x cvt-once, W DMA-staged, XCD swizzle, double-buffered, (256,2).
// R19 lesson: nt stores on m-map tripled HBM WRITE (L2 write-combining lost) -> regular
// stores restored. 11 k-loop variants all confirm the 2-phase structural ceiling (m233).
__launch_bounds__(256, 2)
__global__ void fused_kernel(const float* __restrict__ x, const __bf16* __restrict__ wh,
                             const float* __restrict__ bias, const float* __restrict__ cls,
                             float* __restrict__ out,
                             float* __restrict__ candQ, float* __restrict__ candK,
                             unsigned* __restrict__ candV) {
  __shared__ __align__(16) union SM {
    __bf16 stg[2][STGE];          // 2 x 25600B; x rows 0..127 @ r*80B, W rows @ 10240 + r*80B
    float bufq[128][68];          // 34816B epilogue redistribution
    float part[4][64][13];
    unsigned partu[4][64][13];
  } sm;

  const int tid = threadIdx.x;
  // XCD-aware swizzle (proven R8/R10)
  const int g = blockIdx.x;            // 0..1535
  const int xcd = g & 7;
  const int r_ = g >> 3;               // 0..191
  const int dblk = r_ % 12;
  const int cg = (r_ / 12) * 8 + xcd;  // chunk-group 0..127
  const int chunk = cg & 31;
  const int b = cg >> 5;

  const int d0 = dblk * 64;
  const int w = tid >> 6, l = tid & 63;
  const int wr = w >> 1, wc = w & 1;   // wave 2x2 over (row-tiles, col-halves)
  const int lg = l >> 4, lc = l & 15;
  const int sq = tid >> 6, sd = tid & 63;

  // x staging roles (k0-independent)
  const int xrow = tid >> 1, xh_ = tid & 1;  // x: row 0..127, 16-float half

  // W staging: 960 slots of 16B (192 rows x 5 slots; slot 4 duplicates slot 3 into pad)
  const char* whc = (const char*)wh;
  unsigned wsoff[4];
#pragma unroll
  for (int i = 0; i < 4; ++i) {
    int sl = tid + (i << 8);
    unsigned off = 0;
    if (sl < 960) {
      int row = sl / 5, o = sl % 5;
      int oc = (o > 3) ? 3 : o;
      off = (unsigned)((((row >> 6) * CDIM + d0 + (row & 63)) * (CDIM * 2)) + oc * 16);
    }
    wsoff[i] = off;
  }

  // per-lane cls/bias constants for its 2 column groups
  float qc2[2], kc2[2], iv2[2], bq2[2], bk2[2], bv2[2];
#pragma unroll
  for (int tc = 0; tc < 2; ++tc) {
    int d = d0 + wc * 32 + tc * 16 + lc;
    float q_ = cls[0 * (BATCH * CDIM) + b * CDIM + d];
    float k_ = cls[1 * (BATCH * CDIM) + b * CDIM + d];
    float v_ = cls[2 * (BATCH * CDIM) + b * CDIM + d];
    qc2[tc] = q_; kc2[tc] = k_;
    iv2[tc] = (q_ * k_) * (1.0f + fabsf(v_));
    bq2[tc] = bias[d]; bk2[tc] = bias[CDIM + d]; bv2[tc] = bias[2 * CDIM + d];
  }

  // persistent Q/K per-thread quarter lists (across subs)
  float tqp[TOPK], tkp[TOPK];
#pragma unroll
  for (int r = 0; r < TOPK; ++r) { tqp[r] = -INFINITY; tkp[r] = -INFINITY; }

  for (int sub = 0; sub < 2; ++sub) {
    const int n0 = 1 + chunk * 256 + sub * 128;
    const float* xrp = x + (size_t)(b * NSEQ + n0 + xrow) * CDIM;  // this thread's x row

    f32x4 acc[4][2][3];
    const f32x4 zz = {0.f, 0.f, 0.f, 0.f};
#pragma unroll
    for (int rt = 0; rt < 4; ++rt)
#pragma unroll
      for (int tc = 0; tc < 2; ++tc)
#pragma unroll
        for (int q = 0; q < 3; ++q) acc[rt][tc][q] = zz;

    // x staging registers
    float4 xa0, xa1, xa2, xa3;

#define LOADT(T)                                                                      \
    {                                                                                 \
      const float* xp = xrp + (T) * KSTEP + xh_ * 16;                                 \
      xa0 = *(const float4*)(xp + 0);                                                 \
      xa1 = *(const float4*)(xp + 4);                                                 \
      xa2 = *(const float4*)(xp + 8);                                                 \
      xa3 = *(const float4*)(xp + 12);                                                \
    }

#define CVTWR(NB)                                                                     \
    {                                                                                 \
      __bf16* base_ = &sm.stg[NB][0];                                                 \
      bf16x8 lo, hi;                                                                  \
      lo[0] = (__bf16)xa0.x; lo[1] = (__bf16)xa0.y; lo[2] = (__bf16)xa0.z; lo[3] = (__bf16)xa0.w; \
      lo[4] = (__bf16)xa1.x; lo[5] = (__bf16)xa1.y; lo[6] = (__bf16)xa1.z; lo[7] = (__bf16)xa1.w; \
      hi[0] = (__bf16)xa2.x; hi[1] = (__bf16)xa2.y; hi[2] = (__bf16)xa2.z; hi[3] = (__bf16)xa2.w; \
      hi[4] = (__bf16)xa3.x; hi[5] = (__bf16)xa3.y; hi[6] = (__bf16)xa3.z; hi[7] = (__bf16)xa3.w; \
      *(bf16x8*)(base_ + xrow * ROWSTRIDE + xh_ * 16) = lo;                           \
      *(bf16x8*)(base_ + xrow * ROWSTRIDE + xh_ * 16 + 8) = hi;                       \
    }

#define WSTAGE(NB, T)                                                                 \
    {                                                                                 \
      __attribute__((address_space(3))) char* db =                                    \
          (__attribute__((address_space(3))) char*)&sm + (NB) * STGB + WOFF;          \
      _Pragma("unroll")                                                               \
      for (int i = 0; i < 4; ++i) {                                                   \
        int sl = tid + (i << 8);                                                      \
        if (sl < 960)                                                                 \
          __builtin_amdgcn_global_load_lds(                                           \
              (const __attribute__((address_space(1))) unsigned*)(const void*)(whc + wsoff[i] + (T) * 64), \
              (__attribute__((address_space(3))) unsigned*)(db + sl * 16), 16, 0, 0); \
      }                                                                               \
    }

    __syncthreads();  // stg region free of prior-phase (bufq) use
    WSTAGE(0, 0);
    LOADT(0);
    CVTWR(0);         // data-dep waits on its own x loads only
    for (int t = 0; t < NT; ++t) {
      __syncthreads();  // buf[t&1] x-writes + W DMA drained
      if (t + 1 < NT) {
        WSTAGE((t + 1) & 1, t + 1);  // async DMA into other buffer
        LOADT(t + 1);                // issue next x loads early
      }
      {
        const __bf16* smc = &sm.stg[t & 1][0];
        bf16x8 bfr[2][3];
#pragma unroll
        for (int tc = 0; tc < 2; ++tc)
#pragma unroll
          for (int q = 0; q < 3; ++q)
            bfr[tc][q] = *(const bf16x8*)(smc + (128 + q * 64 + wc * 32 + tc * 16 + lc) * ROWSTRIDE + lg * 8);
#pragma unroll
        for (int rt = 0; rt < 4; ++rt) {
          bf16x8 af = *(const bf16x8*)(smc + (wr * 64 + rt * 16 + lc) * ROWSTRIDE + lg * 8);
#pragma unroll
          for (int tc = 0; tc < 2; ++tc)
#pragma unroll
            for (int q = 0; q < 3; ++q)
              acc[rt][tc][q] = __builtin_amdgcn_mfma_f32_16x16x32_bf16(af, bfr[tc][q], acc[rt][tc][q], 0, 0, 0);
        }
      }
      if (t + 1 < NT) CVTWR((t + 1) & 1);  // write other buffer (disjoint from reads)
    }
#undef LOADT
#undef CVTWR
#undef WSTAGE
    __syncthreads();  // last tile's ds_reads done before bufq overwrite

    // bias
#pragma unroll
    for (int rt = 0; rt < 4; ++rt)
#pragma unroll
      for (int tc = 0; tc < 2; ++tc)
#pragma unroll
        for (int r = 0; r < 4; ++r) {
          acc[rt][tc][0][r] += bq2[tc];
          acc[rt][tc][1][r] += bk2[tc];
          acc[rt][tc][2][r] += bv2[tc];
        }

    // ======== pass V: m = v^2+2v+iv
#pragma unroll
    for (int rt = 0; rt < 4; ++rt)
#pragma unroll
      for (int tc = 0; tc < 2; ++tc)
#pragma unroll
        for (int r = 0; r < 4; ++r) {
          float v = acc[rt][tc][2][r];
          sm.bufq[wr * 64 + rt * 16 + lg * 4 + r][wc * 32 + tc * 16 + lc] = fmaf(v, v + 2.0f, iv2[tc]);
        }
    __syncthreads();
    unsigned tv[PCV];
#pragma unroll
    for (int r = 0; r < PCV; ++r) tv[r] = 0u;
    {
      const int gb = chunk * 256 + sub * 128;
      for (int t = sq * 32; t < sq * 32 + 32; ++t)
        ins_u<PCV>(sortkey(sm.bufq[t][sd], gb + t), tv);
    }
    {  // m-map -> out rows (regular stores: L2 write-combining, proven R17)
      int row = tid >> 1, h = tid & 1;
      float* orow = out + ((size_t)(b * NSEQ + n0 + row)) * CDIM + d0 + h * 32;
#pragma unroll
      for (int i = 0; i < 8; ++i)
        *(float4*)(orow + i * 4) = *(const float4*)&sm.bufq[row][h * 32 + i * 4];
    }
    __syncthreads();
#pragma unroll
    for (int r = 0; r < PCV; ++r) sm.partu[sq][sd][r] = tv[r];
    __syncthreads();
    if (tid < 64) {
      for (int qq = 1; qq < 4; ++qq)
#pragma unroll
        for (int r = 0; r < PCV; ++r) ins_u<PCV>(sm.partu[qq][tid][r], tv);
      size_t base = ((size_t)(b * CDIM + d0 + tid) * NSUB + (chunk * 2 + sub)) * PCV;
#pragma unroll
      for (int r = 0; r < PCV; ++r) candV[base + r] = tv[r];
    }

    // ======== pass Q: a_q = q_cls*k + q
    __syncthreads();
#pragma unroll
    for (int rt = 0; rt < 4; ++rt)
#pragma unroll
      for (int tc = 0; tc < 2; ++tc)
#pragma unroll
        for (int r = 0; r < 4; ++r)
          sm.bufq[wr * 64 + rt * 16 + lg * 4 + r][wc * 32 + tc * 16 + lc] =
              fmaf(qc2[tc], acc[rt][tc][1][r], acc[rt][tc][0][r]);
    __syncthreads();
    for (int t = sq * 32; t < sq * 32 + 32; ++t) ins_f(sm.bufq[t][sd], tqp);

    // ======== pass K: a_k = k_cls*q + k
    __syncthreads();
#pragma unroll
    for (int rt = 0; rt < 4; ++rt)
#pragma unroll
      for (int tc = 0; tc < 2; ++tc)
#pragma unroll
        for (int r = 0; r < 4; ++r)
          sm.bufq[wr * 64 + rt * 16 + lg * 4 + r][wc * 32 + tc * 16 + lc] =
              fmaf(kc2[tc], acc[rt][tc][0][r], acc[rt][tc][1][r]);
    __syncthreads();
    for (int t = sq * 32; t < sq * 32 + 32; ++t) ins_f(sm.bufq[t][sd], tkp);
    // next sub's top barrier protects stg overwrite of bufq
  }  // sub

  // ---- merge Q partials, write candQ
  __syncthreads();
#pragma unroll
  for (int r = 0; r < TOPK; ++r) sm.part[sq][sd][r] = tqp[r];
  __syncthreads();
  if (tid < 64) {
    for (int qq = 1; qq < 4; ++qq)
#pragma unroll
      for (int r = 0; r < TOPK; ++r) ins_f(sm.part[qq][tid][r], tqp);
    size_t base = ((size_t)(b * CDIM + d0 + tid) * NCHUNK + chunk) * TOPK;
#pragma unroll
    for (int r = 0; r < TOPK; ++r) candQ[base + r] = tqp[r];
  }
  // ---- merge K partials, write candK
  __syncthreads();
#pragma unroll
  for (int r = 0; r < TOPK; ++r) sm.part[sq][sd][r] = tkp[r];
  __syncthreads();
  if (tid < 64) {
    for (int qq = 1; qq < 4; ++qq)
#pragma unroll
      for (int r = 0; r < TOPK; ++r) ins_f(sm.part[qq][tid][r], tkp);
    size_t base = ((size_t)(b * CDIM + d0 + tid) * NCHUNK + chunk) * TOPK;
#pragma unroll
    for (int r = 0; r < TOPK; ++r) candK[base + r] = tkp[r];
  }
}

// ---------- kernel C+E fused: merges, 32 pairs x 8 groups (grid 96) ----------
__global__ void merge2_kernel(const float* __restrict__ cls,
                              const float* __restrict__ candQ, const float* __restrict__ candK,
                              const unsigned* __restrict__ candV,
                              float* __restrict__ qm, float* __restrict__ km,
                              float* __restrict__ vm, int* __restrict__ cVi) {
  __shared__ union {
    struct { float pq[8][32][13]; float pk[8][32][13]; } qk;
    unsigned pu[8][32][NCAND];
  } s;
  const int tid = threadIdx.x;
  const int c = tid & 31;
  const int q = tid >> 5;              // group 0..7
  const int pr = blockIdx.x * 32 + c;  // (b,d) pair index

  // ---- phase A: Q/K merge (group scans NCHUNK/8 = 4 chunks)
  float tq[TOPK], tk[TOPK];
#pragma unroll
  for (int r = 0; r < TOPK; ++r) { tq[r] = -INFINITY; tk[r] = -INFINITY; }
  {
    size_t base = ((size_t)pr * NCHUNK + q * 4) * TOPK;
    for (int cc = 0; cc < 4 * TOPK; ++cc) {
      ins_f(candQ[base + cc], tq);
      ins_f(candK[base + cc], tk);
    }
  }
#pragma unroll
  for (int r = 0; r < TOPK; ++r) { s.qk.pq[q][c][r] = tq[r]; s.qk.pk[q][c][r] = tk[r]; }
  __syncthreads();
  if (tid < 32) {
    for (int qq = 1; qq < 8; ++qq)
#pragma unroll
      for (int r = 0; r < TOPK; ++r) { ins_f(s.qk.pq[qq][tid][r], tq); ins_f(s.qk.pk[qq][tid][r], tk); }
    int pr2 = blockIdx.x * 32 + tid;
    int b = pr2 / CDIM, d = pr2 % CDIM;
    qm[(size_t)(b * 13 + 0) * CDIM + d] = cls[0 * (BATCH * CDIM) + b * CDIM + d];
    km[(size_t)(b * 13 + 0) * CDIM + d] = cls[1 * (BATCH * CDIM) + b * CDIM + d];
    vm[(size_t)(b * 13 + 0) * CDIM + d] = cls[2 * (BATCH * CDIM) + b * CDIM + d];
#pragma unroll
    for (int r = 0; r < TOPK; ++r) {
      qm[(size_t)(b * 13 + 1 + r) * CDIM + d] = tq[r];
      km[(size_t)(b * 13 + 1 + r) * CDIM + d] = tk[r];
    }
  }
  __syncthreads();  // phase A LDS reads done before phase B overwrites (union)

  // ---- phase B: V merge -> global top-16 indices (group scans NSUB/8 = 8 subchunks)
  unsigned lv[NCAND];
#pragma unroll
  for (int r = 0; r < NCAND; ++r) lv[r] = 0u;
  {
    size_t base = ((size_t)pr * NSUB + q * 8) * PCV;
    for (int i = 0; i < 8 * PCV; ++i) ins_u<NCAND>(candV[base + i], lv);
  }
#pragma unroll
  for (int r = 0; r < NCAND; ++r) s.pu[q][c][r] = lv[r];
  __syncthreads();
  if (tid < 32) {
    for (int qq = 1; qq < 8; ++qq)
#pragma unroll
      for (int r = 0; r < NCAND; ++r) ins_u<NCAND>(s.pu[qq][tid][r], lv);
    size_t ob = (size_t)(blockIdx.x * 32 + tid) * NCAND;
#pragma unroll
    for (int r = 0; r < NCAND; ++r) cVi[ob + r] = (int)(lv[r] & 0x1FFFu);
  }
}

// ---------- kernel F+D1 fused: fp64 rescore (blocks x<768) | 13x13 QK^T+softmax (x==768) ----------
__global__ void rescore_attn1_kernel(const float* __restrict__ x, const float* __restrict__ W,
                                     const float* __restrict__ bias, const float* __restrict__ cls,
                                     const int* __restrict__ cVi,
                                     const float* __restrict__ qm, const float* __restrict__ km,
                                     float* __restrict__ vm, int* __restrict__ vidx,
                                     float* __restrict__ attw) {
  const int tid = threadIdx.x;
  const int b = blockIdx.y;
  __shared__ union {
    struct { float wrow[CDIM]; int sidx[NCAND]; double sval[NCAND]; } rs;
    float att[13][16];
  } s;

  if (blockIdx.x == CDIM) {
    // ---- attn1: qm/km complete (merge2 launched earlier on stream)
    if (tid < 169) {
      int i = tid / 13, j = tid % 13;
      const float* qr = qm + (size_t)(b * 13 + i) * CDIM;
      const float* kr = km + (size_t)(b * 13 + j) * CDIM;
      float s0 = 0.f, s1 = 0.f, s2 = 0.f, s3 = 0.f;
      for (int c = 0; c < CDIM; c += 4) {
        s0 = fmaf(qr[c + 0], kr[c + 0], s0);
        s1 = fmaf(qr[c + 1], kr[c + 1], s1);
        s2 = fmaf(qr[c + 2], kr[c + 2], s2);
        s3 = fmaf(qr[c + 3], kr[c + 3], s3);
      }
      s.att[i][j] = ((s0 + s1) + (s2 + s3)) * 0.03608439182435161f;  // 768^-0.5
    }
    __syncthreads();
    if (tid < 13) {
      float mx = -INFINITY;
      float e[13];
#pragma unroll
      for (int j = 0; j < 13; ++j) mx = fmaxf(mx, s.att[tid][j]);
      float sum = 0.f;
#pragma unroll
      for (int j = 0; j < 13; ++j) { e[j] = expf(s.att[tid][j] - mx); sum += e[j]; }
      float inv = 1.f / sum;
#pragma unroll
      for (int j = 0; j < 13; ++j) attw[(b * 13 + tid) * 16 + j] = e[j] * inv;
    }
    return;
  }

  // ---- rescore: d = blockIdx.x ; wave w covers candidates [w*4, w*4+4)
  const int d = blockIdx.x;
  const int w = tid >> 6, l = tid & 63;
  if (tid < 192) *(float4*)&s.rs.wrow[tid * 4] = *(const float4*)(W + (size_t)(2 * CDIM + d) * CDIM + tid * 4);
  if (tid >= 192 && tid < 192 + NCAND)
    s.rs.sidx[tid - 192] = cVi[((size_t)b * CDIM + d) * NCAND + (tid - 192)];
  __syncthreads();
#pragma unroll
  for (int c8 = 0; c8 < NCAND / 4; ++c8) {
    const int c = w * (NCAND / 4) + c8;
    const float* xr = x + ((size_t)b * NSEQ + 1 + s.rs.sidx[c]) * CDIM + l * 12;
    const float* wp = &s.rs.wrow[l * 12];
    float4 a0 = *(const float4*)xr;
    float4 a1 = *(const float4*)(xr + 4);
    float4 a2 = *(const float4*)(xr + 8);
    double sdot = 0.0;
    sdot = fma((double)a0.x, (double)wp[0], sdot);
    sdot = fma((double)a0.y, (double)wp[1], sdot);
    sdot = fma((double)a0.z, (double)wp[2], sdot);
    sdot = fma((double)a0.w, (double)wp[3], sdot);
    sdot = fma((double)a1.x, (double)wp[4], sdot);
    sdot = fma((double)a1.y, (double)wp[5], sdot);
    sdot = fma((double)a1.z, (double)wp[6], sdot);
    sdot = fma((double)a1.w, (double)wp[7], sdot);
    sdot = fma((double)a2.x, (double)wp[8], sdot);
    sdot = fma((double)a2.y, (double)wp[9], sdot);
    sdot = fma((double)a2.z, (double)wp[10], sdot);
    sdot = fma((double)a2.w, (double)wp[11], sdot);
#pragma unroll
    for (int off = 32; off > 0; off >>= 1) sdot += __shfl_xor(sdot, off, 64);  // deterministic tree
    if (l == 0) s.rs.sval[c] = sdot;
  }
  __syncthreads();
  if (tid < NCAND) {
    double v = s.rs.sval[tid] + (double)bias[2 * CDIM + d];
    double qc = (double)cls[0 * (BATCH * CDIM) + b * CDIM + d];
    double kc = (double)cls[1 * (BATCH * CDIM) + b * CDIM + d];
    double vc = (double)cls[2 * (BATCH * CDIM) + b * CDIM + d];
    double ivd = (qc * kc) * (1.0 + fabs(vc));
    s.rs.sval[tid] = fma(v, v + 2.0, ivd);
  }
  __syncthreads();
  if (tid == 0) {
    double lv[TOPK];
    int li[TOPK];
#pragma unroll
    for (int r = 0; r < TOPK; ++r) { lv[r] = -INFINITY; li[r] = 0x7fffffff; }
    for (int cc = 0; cc < NCAND; ++cc) ins_di(s.rs.sval[cc], s.rs.sidx[cc], lv, li);
#pragma unroll
    for (int r = 0; r < TOPK; ++r) {
      vm[(size_t)(b * 13 + 1 + r) * CDIM + d] = (float)lv[r];
      vidx[(size_t)(b * TOPK + r) * CDIM + d] = li[r];
    }
  }
}

// ---------- kernel D2: PV + scatter-add (one block per (b, out-row)) ----------
__global__ void attn2_kernel(const float* __restrict__ attw, const float* __restrict__ vm,
                             const int* __restrict__ vidx, float* __restrict__ out) {
  const int b = blockIdx.x, j = blockIdx.y, tid = threadIdx.x;
  __shared__ float arow[13];
  if (tid < 13) arow[tid] = attw[(b * 13 + j) * 16 + tid];
  __syncthreads();
  for (int d = tid; d < CDIM; d += 256) {
    float s = 0.f;
#pragma unroll
    for (int kk = 0; kk < 13; ++kk) s = fmaf(arow[kk], vm[(size_t)(b * 13 + kk) * CDIM + d], s);
    if (j == 0) {
      out[(size_t)b * NSEQ * CDIM + d] = s;
    } else {
      int t = vidx[(size_t)(b * TOPK + (j - 1)) * CDIM + d];
      out[((size_t)b * NSEQ + 1 + t) * CDIM + d] += s;
    }
  }
}

extern "C" void kernel_launch(void* const* d_in, const int* in_sizes, int n_in,
                              void* d_out, int out_size, void* d_ws, size_t ws_size,
                              hipStream_t stream) {
  const float* x = (const float*)d_in[0];
  const float* W = (const float*)d_in[1];
  const float* bias = (const float*)d_in[2];
  float* out = (float*)d_out;
  char* ws = (char*)d_ws;

  // R5-proven workspace layout: total 23,470,080 bytes
  float* cls = (float*)(ws + 0);               // 36864
  float* qm = (float*)(ws + 36864);            // 159744
  float* km = (float*)(ws + 196608);           // 159744
  float* vm = (float*)(ws + 356352);           // 159744
  int* vidx = (int*)(ws + 516096);             // 147456
  float* candQ = (float*)(ws + 663552);        // 4718592
  float* candK = (float*)(ws + 5382144);       // 4718592
  unsigned* candV = (unsigned*)(ws + 10100736);// 9437184
  int* cVi = (int*)(ws + 19537920);            // 393216 (16/pair used)
  __bf16* wh = (__bf16*)(ws + 19931136);       // 3538944 -> total 23470080
  float* attw = (float*)(ws + 663552);         // aliases candQ (dead after merge2)

  hipLaunchKernelGGL(cls_wconv_kernel, dim3(NCLSB + 1728), dim3(256), 0, stream, x, W, bias, cls, wh);
  hipLaunchKernelGGL(fused_kernel, dim3(NDBLK * NCHUNK * BATCH), dim3(256), 0, stream,
                     x, wh, bias, cls, out, candQ, candK, candV);
  hipLaunchKernelGGL(merge2_kernel, dim3(BATCH * CDIM / 32), dim3(256), 0, stream,
                     cls, candQ, candK, candV, qm, km, vm, cVi);
  hipLaunchKernelGGL(rescore_attn1_kernel, dim3(CDIM + 1, BATCH), dim3(256), 0, stream,
                     x, W, bias, cls, cVi, qm, km, vm, vidx, attw);
  hipLaunchKernelGGL(attn2_kernel, dim3(BATCH, 13), dim3(256), 0, stream, attw, vm, vidx, out);
}